// Round 14
// baseline (34.244 us; speedup 1.0000x reference)
//
#include <hip/hip_runtime.h>

#define B_DIM 256
#define L_DIM 32768
#define CHUNK 2048
#define HALO  100
#define NTOT  (CHUNK + 2*HALO)   // 2248
#define NG    (NTOT/4)           // 562 float4 groups
#define T     256
#define EPT   9                  // ceil(NTOT / T)
#define NCH   4                  // chunks per block (software-pipelined)
#define NR    3                  // load rounds per chunk: ceil(NG/T)

typedef float fx4 __attribute__((ext_vector_type(4)));

__device__ __forceinline__ void issue_loads(const float* __restrict__ xr, int chunk0,
                                            int tid, fx4 p[NR]) {
    #pragma unroll
    for (int r = 0; r < NR; ++r) {
        const int g = tid + r * T;
        if (g < NG) {
            const int c = chunk0 - HALO + 4 * g;   // 4-aligned (HALO%4==0)
            if (c >= 0 && c + 3 < L_DIM) {
                p[r] = *reinterpret_cast<const fx4*>(xr + c);
            } else {
                p[r].x = (c + 0 >= 0 && c + 0 < L_DIM) ? xr[c + 0] : 0.0f;
                p[r].y = (c + 1 >= 0 && c + 1 < L_DIM) ? xr[c + 1] : 0.0f;
                p[r].z = (c + 2 >= 0 && c + 2 < L_DIM) ? xr[c + 2] : 0.0f;
                p[r].w = (c + 3 >= 0 && c + 3 < L_DIM) ? xr[c + 3] : 0.0f;
            }
        }
    }
}

__global__ __launch_bounds__(T) void pool_feat_kernel(const float* __restrict__ x,
                                                      float* __restrict__ out) {
    const int row  = blockIdx.y;
    const int base = blockIdx.x * (CHUNK * NCH);
    const int tid  = threadIdx.x;

    // sA holds, in sequence: raw x -> signed-log u -> a-cumsum. All in-place
    // overwrites are own-thread-segment with barriers before cross-thread reads.
    __shared__ __align__(16) float sA[NTOT];
    __shared__ __align__(16) float sB[NTOT];
    __shared__ float waveA[4];
    __shared__ float waveB[4];

    const float* xr = x + (size_t)row * L_DIM;

    fx4 pc[NR], pn[NR];
    issue_loads(xr, base, tid, pc);            // chunk 0 raw -> regs

    for (int k = 0; k < NCH; ++k) {
        const int chunk0 = base + k * CHUNK;

        // Stage current chunk's raw data into LDS
        #pragma unroll
        for (int r = 0; r < NR; ++r) {
            const int g = tid + r * T;
            if (g < NG) *reinterpret_cast<fx4*>(&sA[4 * g]) = pc[r];
        }
        // Prefetch next chunk: loads stay in flight through this chunk's
        // compute + store phases (consumed only at next iteration's staging).
        if (k + 1 < NCH) issue_loads(xr, chunk0 + CHUNK, tid, pn);
        __syncthreads();

        // Pass 1: transform in place + segment totals.
        // u = copysign(log(1+|x|), x); a-term = max(u,0), b-term = max(-u,0)
        // (log(max(1,1+x)) and log(max(1,1-x)) are never both nonzero).
        const int s0 = tid * EPT;
        const int s1 = min(NTOT, s0 + EPT);
        float runA = 0.0f, runB = 0.0f;
        for (int j = s0; j < s1; ++j) {
            const float v = sA[j];
            const float t = __logf(1.0f + fabsf(v));
            const float u = copysignf(t, v);
            runA += fmaxf(u, 0.0f);
            runB += fmaxf(-u, 0.0f);
            sA[j] = u;                         // raw consumed, store signed log
        }

        // Block scan of segment totals (wave shuffle + wave totals)
        float vA = runA, vB = runB;
        const int lane = tid & 63;
        const int wid  = tid >> 6;
        #pragma unroll
        for (int d = 1; d < 64; d <<= 1) {
            float uA = __shfl_up(vA, d);
            float uB = __shfl_up(vB, d);
            if (lane >= d) { vA += uA; vB += uB; }
        }
        if (lane == 63) { waveA[wid] = vA; waveB[wid] = vB; }
        __syncthreads();
        float offA = vA - runA;                // exclusive prefix within wave
        float offB = vB - runB;
        #pragma unroll
        for (int w = 0; w < 3; ++w) {
            if (w < wid) { offA += waveA[w]; offB += waveB[w]; }
        }

        // Pass 2: rebuild terms from u (no log recompute), write final cumsums
        float accA = offA, accB = offB;
        for (int j = s0; j < s1; ++j) {
            const float u = sA[j];
            accA += fmaxf(u, 0.0f);
            accB += fmaxf(-u, 0.0f);
            sA[j] = accA;
            sB[j] = accB;
        }
        __syncthreads();

        // Phase 5: windows via aligned ds_read_b128 only; shifted windows
        // assembled by register selects from adjacent float4s.
        const float inv3   = 1.0f / 3.0f;
        const float inv199 = 1.0f / 199.0f;
        float* ob = out + (size_t)row * 4u * L_DIM + chunk0;
        #pragma unroll
        for (int it = 0; it < CHUNK / (4 * T); ++it) {   // 2 iterations
            const int i0 = 4 * (tid + it * T);
            fx4 r0, r1, r2, r3;
            #pragma unroll
            for (int arr = 0; arr < 2; ++arr) {
                const float* s = arr ? sB : sA;
                const fx4 L0 = *reinterpret_cast<const fx4*>(s + i0);
                const fx4 L1 = *reinterpret_cast<const fx4*>(s + i0 + 96);
                const fx4 L2 = *reinterpret_cast<const fx4*>(s + i0 + 100);
                const fx4 L3 = *reinterpret_cast<const fx4*>(s + i0 + 104);
                const fx4 L4 = *reinterpret_cast<const fx4*>(s + i0 + 196);
                const fx4 L5 = *reinterpret_cast<const fx4*>(s + i0 + 200);
                const float csI[4]   = {L0.x, L0.y, L0.z, L0.w};
                const float cs98[4]  = {L1.z, L1.w, L2.x, L2.y};
                const float cs101[4] = {L2.y, L2.z, L2.w, L3.x};
                const float cs199[4] = {L4.w, L5.x, L5.y, L5.z};
                fx4& rs = arr ? r3 : r1;   // plain k=3 pool
                fx4& rd = arr ? r2 : r0;   // k=3 - k=199
                #pragma unroll
                for (int u = 0; u < 4; ++u) {
                    const float p0 = (cs101[u] - cs98[u]) * inv3;
                    const float p5 = (cs199[u] - csI[u]) * inv199;
                    rs[u] = p0;
                    rd[u] = p0 - p5;
                }
            }
            *reinterpret_cast<fx4*>(ob + 0 * (size_t)L_DIM + i0) = r0;
            *reinterpret_cast<fx4*>(ob + 1 * (size_t)L_DIM + i0) = r1;
            *reinterpret_cast<fx4*>(ob + 2 * (size_t)L_DIM + i0) = r2;
            *reinterpret_cast<fx4*>(ob + 3 * (size_t)L_DIM + i0) = r3;
        }

        if (k + 1 < NCH) {
            __syncthreads();                   // sA reads done before restaging
            #pragma unroll
            for (int r = 0; r < NR; ++r) pc[r] = pn[r];
        }
    }
}

extern "C" void kernel_launch(void* const* d_in, const int* in_sizes, int n_in,
                              void* d_out, int out_size, void* d_ws, size_t ws_size,
                              hipStream_t stream) {
    const float* x = (const float*)d_in[0];
    float* out = (float*)d_out;
    dim3 grid(L_DIM / (CHUNK * NCH), B_DIM);
    pool_feat_kernel<<<grid, dim3(T), 0, stream>>>(x, out);
}

// Round 16
// 32.088 us; speedup vs baseline: 1.0672x; 1.0672x over previous
//
#include <hip/hip_runtime.h>

#define B_DIM 256
#define L_DIM 32768
#define CHUNK 2048
#define HALO  100
#define NTOT  (CHUNK + 2*HALO)   // 2248
#define NTOTP 2256               // padded to EPT*NSEG
#define T     256
#define EPT   12                 // contiguous elements per thread
#define NSEG  188                // ceil(NTOT/EPT); threads >= NSEG idle in transform
#define NCH   2                  // chunks per block (software-pipelined)

typedef float fx4 __attribute__((ext_vector_type(4)));

// Contiguous 12-element load per thread (3 x float4, 16B-aligned since
// 12*tid - 100 is a multiple of 4). Zero-fill outside the row / past NTOT.
__device__ __forceinline__ void issue_loads(const float* __restrict__ xr, int chunk0,
                                            int tid, fx4 p[3]) {
    if (tid >= NSEG) {
        p[0] = (fx4)0.0f; p[1] = (fx4)0.0f; p[2] = (fx4)0.0f;
        return;
    }
    const int gbase = chunk0 - HALO + EPT * tid;
    if (tid < NSEG - 1 && gbase >= 0 && gbase + EPT <= L_DIM) {
        p[0] = *reinterpret_cast<const fx4*>(xr + gbase);
        p[1] = *reinterpret_cast<const fx4*>(xr + gbase + 4);
        p[2] = *reinterpret_cast<const fx4*>(xr + gbase + 8);
    } else {
        const int idx0 = EPT * tid;
        #pragma unroll
        for (int r = 0; r < 3; ++r) {
            #pragma unroll
            for (int c = 0; c < 4; ++c) {
                const int idx = idx0 + 4 * r + c;
                const int col = gbase + 4 * r + c;
                p[r][c] = (idx < NTOT && col >= 0 && col < L_DIM) ? xr[col] : 0.0f;
            }
        }
    }
}

__global__ __launch_bounds__(T) void pool_feat_kernel(const float* __restrict__ x,
                                                      float* __restrict__ out) {
    const int row  = blockIdx.y;
    const int base = blockIdx.x * (CHUNK * NCH);
    const int tid  = threadIdx.x;

    // Only the FINAL cumsums live in LDS — raw x never touches LDS.
    __shared__ __align__(16) float sA[NTOTP];
    __shared__ __align__(16) float sB[NTOTP];
    __shared__ float waveA[4];
    __shared__ float waveB[4];

    const float* xr = x + (size_t)row * L_DIM;

    fx4 pc[3], pn[3];
    issue_loads(xr, base, tid, pc);            // chunk 0 raw -> regs

    for (int k = 0; k < NCH; ++k) {
        const int chunk0 = base + k * CHUNK;

        // Prefetch next chunk; in flight through transform+scan+store phases.
        if (k + 1 < NCH) issue_loads(xr, chunk0 + CHUNK, tid, pn);

        // Transform + thread-local running totals, entirely in registers.
        // u = copysign(log(1+|x|), x); a-term = max(u,0), b-term = max(-u,0)
        // (log(max(1,1+x)) and log(max(1,1-x)) are never both nonzero).
        float u[EPT];
        float runA = 0.0f, runB = 0.0f;
        #pragma unroll
        for (int r = 0; r < 3; ++r) {
            #pragma unroll
            for (int c = 0; c < 4; ++c) {
                const float v  = pc[r][c];
                const float t  = __logf(1.0f + fabsf(v));
                const float uu = copysignf(t, v);
                runA += fmaxf(uu, 0.0f);
                runB += fmaxf(-uu, 0.0f);
                u[4 * r + c] = uu;
            }
        }

        // Block scan of segment totals (wave shuffle + wave totals)
        float vA = runA, vB = runB;
        const int lane = tid & 63;
        const int wid  = tid >> 6;
        #pragma unroll
        for (int d = 1; d < 64; d <<= 1) {
            float uA = __shfl_up(vA, d);
            float uB = __shfl_up(vB, d);
            if (lane >= d) { vA += uA; vB += uB; }
        }
        if (lane == 63) { waveA[wid] = vA; waveB[wid] = vB; }
        __syncthreads();                                   // barrier 1
        float offA = vA - runA;                // exclusive prefix within wave
        float offB = vB - runB;
        #pragma unroll
        for (int w = 0; w < 3; ++w) {
            if (w < wid) { offA += waveA[w]; offB += waveB[w]; }
        }

        // Write final cumsums (contiguous 12 floats/thread, 3x b128 each)
        if (tid < NSEG) {
            float accA = offA, accB = offB;
            const int s0 = EPT * tid;
            #pragma unroll
            for (int r = 0; r < 3; ++r) {
                fx4 wa, wb;
                #pragma unroll
                for (int c = 0; c < 4; ++c) {
                    const float uu = u[4 * r + c];
                    accA += fmaxf(uu, 0.0f);
                    accB += fmaxf(-uu, 0.0f);
                    wa[c] = accA;
                    wb[c] = accB;
                }
                *reinterpret_cast<fx4*>(&sA[s0 + 4 * r]) = wa;
                *reinterpret_cast<fx4*>(&sB[s0 + 4 * r]) = wb;
            }
        }
        __syncthreads();                                   // barrier 2

        // Phase 5: windows via aligned ds_read_b128 only; shifted windows
        // assembled by register selects from adjacent float4s.
        const float inv3   = 1.0f / 3.0f;
        const float inv199 = 1.0f / 199.0f;
        float* ob = out + (size_t)row * 4u * L_DIM + chunk0;
        #pragma unroll
        for (int it = 0; it < CHUNK / (4 * T); ++it) {   // 2 iterations
            const int i0 = 4 * (tid + it * T);
            fx4 r0, r1, r2, r3;
            #pragma unroll
            for (int arr = 0; arr < 2; ++arr) {
                const float* s = arr ? sB : sA;
                const fx4 L0 = *reinterpret_cast<const fx4*>(s + i0);
                const fx4 L1 = *reinterpret_cast<const fx4*>(s + i0 + 96);
                const fx4 L2 = *reinterpret_cast<const fx4*>(s + i0 + 100);
                const fx4 L3 = *reinterpret_cast<const fx4*>(s + i0 + 104);
                const fx4 L4 = *reinterpret_cast<const fx4*>(s + i0 + 196);
                const fx4 L5 = *reinterpret_cast<const fx4*>(s + i0 + 200);
                const float csI[4]   = {L0.x, L0.y, L0.z, L0.w};
                const float cs98[4]  = {L1.z, L1.w, L2.x, L2.y};
                const float cs101[4] = {L2.y, L2.z, L2.w, L3.x};
                const float cs199[4] = {L4.w, L5.x, L5.y, L5.z};
                fx4& rs = arr ? r3 : r1;   // plain k=3 pool
                fx4& rd = arr ? r2 : r0;   // k=3 - k=199
                #pragma unroll
                for (int q = 0; q < 4; ++q) {
                    const float p0 = (cs101[q] - cs98[q]) * inv3;
                    const float p5 = (cs199[q] - csI[q]) * inv199;
                    rs[q] = p0;
                    rd[q] = p0 - p5;
                }
            }
            *reinterpret_cast<fx4*>(ob + 0 * (size_t)L_DIM + i0) = r0;
            *reinterpret_cast<fx4*>(ob + 1 * (size_t)L_DIM + i0) = r1;
            *reinterpret_cast<fx4*>(ob + 2 * (size_t)L_DIM + i0) = r2;
            *reinterpret_cast<fx4*>(ob + 3 * (size_t)L_DIM + i0) = r3;
        }

        if (k + 1 < NCH) {
            __syncthreads();                 // phase-5 reads done before rewrite
            #pragma unroll
            for (int r = 0; r < 3; ++r) pc[r] = pn[r];
        }
    }
}

extern "C" void kernel_launch(void* const* d_in, const int* in_sizes, int n_in,
                              void* d_out, int out_size, void* d_ws, size_t ws_size,
                              hipStream_t stream) {
    const float* x = (const float*)d_in[0];
    float* out = (float*)d_out;
    dim3 grid(L_DIM / (CHUNK * NCH), B_DIM);
    pool_feat_kernel<<<grid, dim3(T), 0, stream>>>(x, out);
}